// Round 9
// baseline (98.384 us; speedup 1.0000x reference)
//
#include <hip/hip_runtime.h>

namespace {

constexpr int N = 20;                  // NEIGHBOR_SIZE
constexpr int ROWS = 5;                // rows per lane
constexpr int GROUPS = 16;             // 4-lane quads per wave = 16 matrices/batch
constexpr int TILE = 4;                // batches per wave (intra-wave s/w pipeline)
constexpr int WAVES_PER_BLOCK = 4;     // 256 threads
constexpr int MATS_PER_WAVE = GROUPS * TILE;               // 64
constexpr int MATS_PER_BLOCK = MATS_PER_WAVE * WAVES_PER_BLOCK;  // 256
constexpr float SIGMA_SQ = 1.0f;
constexpr float PHI = 0.5f;
constexpr float TAU = 0.1f;
// exp(-phi*d) = 2^(-phi*log2(e)*d): pre-scale coords by C = phi*log2(e); the
// negate folds into the v_exp_f32 input modifier.
constexpr float CSCALE = 0.72134752f;  // PHI * log2(e)

// Broadcast lane SRC of each 4-lane quad to all 4 lanes: DPP quad_perm,
// pure VALU (per-SIMD pipe) -- no LDS traffic.
template <int SRC>
__device__ __forceinline__ float qbcast(float x) {
  constexpr int CTRL = SRC * 0x55;     // quad_perm:[SRC,SRC,SRC,SRC]
  return __builtin_bit_cast(
      float, __builtin_amdgcn_mov_dpp(__builtin_bit_cast(int, x), CTRL, 0xF,
                                      0xF, true));
}

// One Gauss-Jordan elimination step; K is a template parameter so every
// array index is compile-time regardless of unroll heuristics (rule #20).
template <int K>
__device__ __forceinline__ void gj_step(float (&a)[ROWS][N], int o,
                                        const float (&ofl)[4]) {
  constexpr int KO = K / ROWS;         // owner lane of row K
  constexpr int KR = K % ROWS;         // owner-local row index
  float r[N];
#pragma unroll
  for (int j = 0; j < N; ++j) r[j] = qbcast<KO>(a[KR][j]);
  const float ip = __builtin_amdgcn_rcpf(r[K]);
  const float fpiv = 1.0f - ip;
#pragma unroll
  for (int rr = 0; rr < ROWS; ++rr) {
    float f = a[rr][K] * ip;
    if (rr == KR) f = (o == KO) ? fpiv : f;  // one cndmask, only on row KR
    const float nf = -f;
#pragma unroll
    for (int j = 0; j < N; ++j) {
      if (j == K) continue;
      a[rr][j] = __builtin_fmaf(nf, r[j], a[rr][j]);
    }
    a[rr][K] = nf;                     // column K: -A[i][K]/p
  }
  a[KR][K] += ofl[KO];                 // owner diag: (1/p - 1) + 1 = 1/p
}

__global__ __launch_bounds__(256, 2) void invcov_kernel(
    const float* __restrict__ pos, float* __restrict__ out, int B) {
  // Per-wave 6.4 KB transpose buffer (4 matrices x 400 floats), reused over
  // 4 store passes x TILE batches. Wave-local only -> lgkmcnt fences.
  __shared__ float lds[WAVES_PER_BLOCK][4 * N * N];

  const int tid  = threadIdx.x;
  const int lane = tid & 63;
  const int wave = tid >> 6;
  const int g    = lane >> 2;          // quad = matrix within batch, 0..15
  const int o    = lane & 3;           // lane within quad, owns rows 5o..5o+4
  const int wbase = blockIdx.x * MATS_PER_BLOCK + wave * MATS_PER_WAVE;
  float* wbuf = &lds[wave][0];

  // Per-quad-lane constant masks, constant-indexed (batch-invariant).
  float tdiag[4], ofl[4];
#pragma unroll
  for (int t = 0; t < 4; ++t) {
    const bool is = (o == t);
    tdiag[t] = is ? (TAU * SIGMA_SQ) : 0.0f;
    ofl[t]   = is ? 1.0f : 0.0f;
  }

  // Intra-wave pipeline: batch t+1's build/GJ VALU work overlaps batch t's
  // in-flight global stores (fire-and-forget; only lgkmcnt is ever waited).
#pragma unroll 1
  for (int t = 0; t < TILE; ++t) {
    const int mbase = wbase + t * GROUPS;   // 16 contiguous matrices
    const int m     = mbase + g;
    const int mc    = (m < B) ? m : (B - 1);
    const float* pm = pos + (size_t)mc * (2 * N);

    // All 20 points in registers, pre-scaled by CSCALE.
    float px[N], py[N];
    {
      const float4* pv = (const float4*)pm;
#pragma unroll
      for (int q = 0; q < N / 2; ++q) {
        const float4 p = pv[q];
        px[2 * q]     = p.x * CSCALE; py[2 * q]     = p.y * CSCALE;
        px[2 * q + 1] = p.z * CSCALE; py[2 * q + 1] = p.w * CSCALE;
      }
    }
    // My 5 rows' coords: runtime offset -> tiny L1-hit loads, no reg-indexing.
    float myx[ROWS], myy[ROWS];
    {
      const float2* pm2 = (const float2*)pm;
#pragma unroll
      for (int rr = 0; rr < ROWS; ++rr) {
        const float2 p = pm2[ROWS * o + rr];
        myx[rr] = p.x * CSCALE; myy[rr] = p.y * CSCALE;
      }
    }

    // Build my 5 rows: a[rr][c] = s^2 * 2^(-C*d) (+ tau*s^2 on my diagonal).
    float a[ROWS][N];
#pragma unroll
    for (int rr = 0; rr < ROWS; ++rr) {
#pragma unroll
      for (int c = 0; c < N; ++c) {
        const float dx = px[c] - myx[rr];
        const float dy = py[c] - myy[rr];
        const float d  = __builtin_amdgcn_sqrtf(__builtin_fmaf(dx, dx, dy * dy));
        float v = SIGMA_SQ * __builtin_amdgcn_exp2f(-d);  // neg -> input mod
        if (c % ROWS == rr) v += tdiag[c / ROWS];
        a[rr][c] = v;
      }
    }

    // 20 explicit template steps: compile-time K everywhere.
    __builtin_amdgcn_s_setprio(1);
    gj_step<0>(a, o, ofl);  gj_step<1>(a, o, ofl);  gj_step<2>(a, o, ofl);
    gj_step<3>(a, o, ofl);  gj_step<4>(a, o, ofl);  gj_step<5>(a, o, ofl);
    gj_step<6>(a, o, ofl);  gj_step<7>(a, o, ofl);  gj_step<8>(a, o, ofl);
    gj_step<9>(a, o, ofl);  gj_step<10>(a, o, ofl); gj_step<11>(a, o, ofl);
    gj_step<12>(a, o, ofl); gj_step<13>(a, o, ofl); gj_step<14>(a, o, ofl);
    gj_step<15>(a, o, ofl); gj_step<16>(a, o, ofl); gj_step<17>(a, o, ofl);
    gj_step<18>(a, o, ofl); gj_step<19>(a, o, ofl);
    __builtin_amdgcn_s_setprio(0);

    if (mbase + GROUPS <= B) {
      // Dense epilogue: 4 passes of 4 matrices. Owning 16 lanes stage 400 B
      // each into LDS; all 64 lanes store the 6400 B chunk contiguously.
#pragma unroll
      for (int p = 0; p < 4; ++p) {
        if ((g >> 2) == p) {
          float* dst = wbuf + (g & 3) * (N * N) + o * (ROWS * N);
#pragma unroll
          for (int rr = 0; rr < ROWS; ++rr) {
#pragma unroll
            for (int q = 0; q < N / 4; ++q) {
              *(float4*)&dst[rr * N + 4 * q] =
                  make_float4(a[rr][4 * q], a[rr][4 * q + 1],
                              a[rr][4 * q + 2], a[rr][4 * q + 3]);
            }
          }
        }
        asm volatile("s_waitcnt lgkmcnt(0)" ::: "memory");

        float* gout = out + (size_t)(mbase + 4 * p) * (N * N);
#pragma unroll
        for (int s = 0; s < 6; ++s) {
          const float4 v = *(const float4*)&wbuf[lane * 4 + s * 256];
          *(float4*)&gout[lane * 4 + s * 256] = v;
        }
        if (lane < 16) {
          const float4 v = *(const float4*)&wbuf[lane * 4 + 6 * 256];
          *(float4*)&gout[lane * 4 + 6 * 256] = v;
        }
        // Reads must land in VGPRs before next pass overwrites the buffer.
        asm volatile("s_waitcnt lgkmcnt(0)" ::: "memory");
      }
    } else if (m < B) {
      // Rare tail: direct (slow) per-lane stores.
      float* om = out + (size_t)m * (N * N) + (ROWS * o) * N;
#pragma unroll
      for (int rr = 0; rr < ROWS; ++rr) {
#pragma unroll
        for (int q = 0; q < N / 4; ++q) {
          *(float4*)&om[rr * N + 4 * q] =
              make_float4(a[rr][4 * q], a[rr][4 * q + 1], a[rr][4 * q + 2],
                          a[rr][4 * q + 3]);
        }
      }
    }
  }
}

}  // namespace

extern "C" void kernel_launch(void* const* d_in, const int* in_sizes, int n_in,
                              void* d_out, int out_size, void* d_ws, size_t ws_size,
                              hipStream_t stream) {
  const float* pos = (const float*)d_in[0];   // [B, 40] f32
  // d_in[1] (edge_list, int64) is unused by the reference computation.
  float* out = (float*)d_out;                 // [B, 20, 20] f32
  const int B = in_sizes[0] / (2 * N);
  const int blocks = (B + MATS_PER_BLOCK - 1) / MATS_PER_BLOCK;
  invcov_kernel<<<blocks, 256, 0, stream>>>(pos, out, B);
}